// Round 11
// baseline (82.895 us; speedup 1.0000x reference)
//
#include <hip/hip_runtime.h>
#include <hip/hip_bf16.h>

// LogicConv3d: B=64, C=32, H=32, W=32, K=64, P=784, S=16 gathers/side.
// R11: R10 + conflict-free LDS via parity-split swizzle + pipe rebalance.
//  - R10's LDS reads: each lane reads 2 adjacent dwords -> lane stride 8B =
//    even banks only = 4-way conflict on every ds_read2 (~15us of main).
//  - R11 stages the even image de-interleaved: element e at dword
//    (e>>1) + (e&1)*16384. Pair (2t,2t+1) reads become addr = sBase +
//    4t + 8*row (stride-1 banks, conflict-free) + a leaf-uniform second
//    read at sDelta (+65536 / -65532 by parity, SALU-precomputed).
//  - Leaves 14,15 take the even image from global (L2-hot) to balance
//    ds (~8.7us) vs VMEM (~8.6us) pipes.
//  - Odd image from global unchanged (adjacent pairs -> dwordx2 merge).

#define B_  64
#define C_  32
#define H_  32
#define W_  32
#define K_  64
#define P_  784
#define CHW (C_*H_*W_)      // 32768 floats = 128 KB
#define HW  (H_*W_)         // 1024
#define SITES (K_*P_)       // 50176
#define NPAIR (P_/2)        // 392
#define NLDS 14             // leaves 0..13 even-img from LDS; 14,15 global

__constant__ float COEF_[16][4] = {
    {0, 0, 0, 0}, {0, 0, 0, 1}, {0, 1, 0, -1}, {0, 1, 0, 0},
    {0, 0, 1, -1}, {0, 0, 1, 0}, {0, 1, 1, -2}, {0, 1, 1, -1},
    {1, -1, -1, 1}, {1, -1, -1, 2}, {1, 0, -1, 0}, {1, 0, -1, 1},
    {1, -1, 0, 0}, {1, -1, 0, 1}, {1, 0, 0, -1}, {1, 0, 0, 0}
};

// ---- kernel 1: tiny prep = bases (0..2047) + coefs (2048..4031) ----
__global__ __launch_bounds__(256) void prep_kernel(
    const int* __restrict__ a_idx, const int* __restrict__ b_idx,
    const float* __restrict__ w0, const float* __restrict__ w1,
    const float* __restrict__ w2, const float* __restrict__ w3,
    const float* __restrict__ w4,
    int* __restrict__ baseAB,        // [K_][32] byte offsets (original layout)
    float4* __restrict__ cws)        // [K_*31]
{
    const int t = blockIdx.x * 256 + threadIdx.x;
    if (t < K_ * 32) {
        const int k = t >> 5;
        const int j = t & 31;
        const int* src = (j < 16) ? a_idx : b_idx;
        const int l = j & 15;
        const size_t ii = ((size_t)k * P_ * 16 + l) * 3;   // site (k, p=0, l)
        const int h = src[ii + 0];
        const int w = src[ii + 1];
        const int c = src[ii + 2];
        baseAB[t] = (c << 12) + (h << 7) + (w << 2);       // bytes
    } else if (t < K_ * 32 + K_ * 31) {
        const int tt = t - K_ * 32;
        const int k = tt / 31;
        const int node = tt - k * 31;
        int d, l;
        if      (node < 16) { d = 0; l = node; }
        else if (node < 24) { d = 1; l = node - 16; }
        else if (node < 28) { d = 2; l = node - 24; }
        else if (node < 30) { d = 3; l = node - 28; }
        else                { d = 4; l = 0; }
        const float* W;
        switch (d) {
            case 0: W = w0; break;
            case 1: W = w1; break;
            case 2: W = w2; break;
            case 3: W = w3; break;
            default: W = w4; break;
        }
        const float* row = W + ((size_t)l * K_ + k) * 16;
        float m = row[0];
        #pragma unroll
        for (int o = 1; o < 16; ++o) m = fmaxf(m, row[o]);
        float e[16];
        float Z = 0.0f;
        #pragma unroll
        for (int o = 0; o < 16; ++o) { e[o] = expf(row[o] - m); Z += e[o]; }
        const float inv = 1.0f / Z;
        float c0 = 0.f, c1 = 0.f, c2 = 0.f, c3 = 0.f;
        #pragma unroll
        for (int o = 0; o < 16; ++o) {
            c0 += e[o] * COEF_[o][0];
            c1 += e[o] * COEF_[o][1];
            c2 += e[o] * COEF_[o][2];
            c3 += e[o] * COEF_[o][3];
        }
        cws[tt] = make_float4(c0 * inv, c1 * inv, c2 * inv, c3 * inv);
    }
}

// y = c0 + c1*a + c2*b + c3*a*b == fma(b, fma(c3,a,c2), fma(c1,a,c0))
__device__ __forceinline__ float binop(float a, float b, float4 c) {
    return fmaf(b, fmaf(c.w, a, c.z), fmaf(c.y, a, c.x));
}

// ---- kernel 2: main. bid = kg*32 + bp. 1024 thr, 1 block/CU. ----
__global__ __launch_bounds__(1024, 4) void logicconv_main(
    const float* __restrict__ x,
    const int* __restrict__ baseAB,
    const float4* __restrict__ cws,
    float* __restrict__ out)
{
    __shared__ float simg[CHW];   // even image, parity-split layout

    const int tid = threadIdx.x;
    const int kg  = blockIdx.x >> 5;   // 0..7  (slow)
    const int bp  = blockIdx.x & 31;   // 0..31 (fast)
    const int b0  = bp * 2;

    // stage EVEN image de-interleaved: elem e -> dword (e>>1) + (e&1)*16384
    {
        const float4* xi = (const float4*)(x + (size_t)b0 * CHW);
        float2* se = (float2*)simg;            // even elements
        float2* so = ((float2*)simg) + 8192;   // odd elements (byte 65536)
        #pragma unroll
        for (int j = 0; j < 8; ++j) {
            const int u = tid + j * 1024;
            const float4 v = xi[u];
            se[u] = make_float2(v.x, v.z);     // elems 4u, 4u+2
            so[u] = make_float2(v.y, v.w);     // elems 4u+1, 4u+3
        }
    }
    __syncthreads();

    // 8 groups of 128 threads; group owns one k (wave-uniform)
    const int g    = __builtin_amdgcn_readfirstlane(tid >> 7);
    const int lane = tid & 127;
    const int k    = kg * 8 + g;

    const int*    __restrict__ bA = baseAB + k * 32;          // s_load
    const float4* __restrict__ cw = cws + (size_t)k * 31;     // s_load

    // per-leaf-side swizzled LDS bases + deltas (all SALU, wave-uniform)
    int sB[2 * NLDS], sD[2 * NLDS];
    #pragma unroll
    for (int j = 0; j < NLDS; ++j) {
        #pragma unroll
        for (int sdx = 0; sdx < 2; ++sdx) {
            const int bo = bA[sdx * 16 + j];       // original byte offset
            const int be = bo >> 2;                // element index
            const int odd = be & 1;
            sB[2*j + sdx] = odd ? (65536 + (((be - 1) >> 1) << 2))
                                : ((be >> 1) << 2);
            sD[2*j + sdx] = odd ? -65532 : 65536;
        }
    }

    const char* sb = (const char*)simg;
    const char* x0g = (const char*)(x + (size_t)b0 * CHW);         // even img
    const char* x1  = (const char*)(x + (size_t)(b0 + 1) * CHW);   // odd img
    float* __restrict__ o0 = out + ((size_t)b0 * K_ + k) * P_;
    float* __restrict__ o1 = o0 + (size_t)K_ * P_;

    for (int s = 0; s < 4; ++s) {
        const int t = s * 128 + lane;          // pair index
        if (t < NPAIR) {
            const unsigned row   = (unsigned)t / 14u;             // (2t)/28
            const unsigned dispL = 4u * (unsigned)t + 8u * row;   // swizzled
            const unsigned dispG = 8u * (unsigned)t + 16u * row;  // original

            float2 ye[16], yo[16];
            #pragma unroll
            for (int h = 0; h < 2; ++h) {
                // ---- 1) odd-image global loads (8 leaves, dwordx2-mergeable)
                float od[32];
                #pragma unroll
                for (int j = 0; j < 8; ++j) {
                    const int l = h * 8 + j;
                    const unsigned ea = (unsigned)bA[l]      + dispG;
                    const unsigned eb = (unsigned)bA[16 + l] + dispG;
                    od[4*j+0] = *(const float*)(x1 + ea);
                    od[4*j+1] = *(const float*)(x1 + ea + 4);
                    od[4*j+2] = *(const float*)(x1 + eb);
                    od[4*j+3] = *(const float*)(x1 + eb + 4);
                }
                // ---- 2) even-image loads: LDS (conflict-free) or global
                float ev[32];
                #pragma unroll
                for (int j = 0; j < 8; ++j) {
                    const int l = h * 8 + j;
                    if (l < NLDS) {
                        const unsigned a0 = (unsigned)sB[2*l]     + dispL;
                        const unsigned b0a = (unsigned)sB[2*l + 1] + dispL;
                        ev[4*j+0] = *(const float*)(sb + a0);
                        ev[4*j+1] = *(const float*)(sb + a0 + sD[2*l]);
                        ev[4*j+2] = *(const float*)(sb + b0a);
                        ev[4*j+3] = *(const float*)(sb + b0a + sD[2*l + 1]);
                    } else {
                        const unsigned ea = (unsigned)bA[l]      + dispG;
                        const unsigned eb = (unsigned)bA[16 + l] + dispG;
                        ev[4*j+0] = *(const float*)(x0g + ea);
                        ev[4*j+1] = *(const float*)(x0g + ea + 4);
                        ev[4*j+2] = *(const float*)(x0g + eb);
                        ev[4*j+3] = *(const float*)(x0g + eb + 4);
                    }
                }
                // ---- 3) layer-0 for this half
                #pragma unroll
                for (int j = 0; j < 8; ++j) {
                    const int l = h * 8 + j;
                    const float4 c = cw[l];
                    ye[l].x = binop(ev[4*j+0], ev[4*j+2], c);
                    ye[l].y = binop(ev[4*j+1], ev[4*j+3], c);
                    yo[l].x = binop(od[4*j+0], od[4*j+2], c);
                    yo[l].y = binop(od[4*j+1], od[4*j+3], c);
                }
            }
            #pragma unroll
            for (int l = 0; l < 8; ++l) {
                const float4 c = cw[16 + l];
                ye[l].x = binop(ye[2*l].x, ye[2*l+1].x, c);
                ye[l].y = binop(ye[2*l].y, ye[2*l+1].y, c);
                yo[l].x = binop(yo[2*l].x, yo[2*l+1].x, c);
                yo[l].y = binop(yo[2*l].y, yo[2*l+1].y, c);
            }
            #pragma unroll
            for (int l = 0; l < 4; ++l) {
                const float4 c = cw[24 + l];
                ye[l].x = binop(ye[2*l].x, ye[2*l+1].x, c);
                ye[l].y = binop(ye[2*l].y, ye[2*l+1].y, c);
                yo[l].x = binop(yo[2*l].x, yo[2*l+1].x, c);
                yo[l].y = binop(yo[2*l].y, yo[2*l+1].y, c);
            }
            #pragma unroll
            for (int l = 0; l < 2; ++l) {
                const float4 c = cw[28 + l];
                ye[l].x = binop(ye[2*l].x, ye[2*l+1].x, c);
                ye[l].y = binop(ye[2*l].y, ye[2*l+1].y, c);
                yo[l].x = binop(yo[2*l].x, yo[2*l+1].x, c);
                yo[l].y = binop(yo[2*l].y, yo[2*l+1].y, c);
            }
            {
                const float4 c = cw[30];
                float2 re, ro;
                re.x = binop(ye[0].x, ye[1].x, c);
                re.y = binop(ye[0].y, ye[1].y, c);
                ro.x = binop(yo[0].x, yo[1].x, c);
                ro.y = binop(yo[0].y, yo[1].y, c);
                *(float2*)(o0 + 2 * t) = re;   // byte 8t -> 8-aligned
                *(float2*)(o1 + 2 * t) = ro;
            }
        }
    }
}

extern "C" void kernel_launch(void* const* d_in, const int* in_sizes, int n_in,
                              void* d_out, int out_size, void* d_ws, size_t ws_size,
                              hipStream_t stream) {
    const float* x     = (const float*)d_in[0];
    const float* w0    = (const float*)d_in[1];
    const float* w1    = (const float*)d_in[2];
    const float* w2    = (const float*)d_in[3];
    const float* w3    = (const float*)d_in[4];
    const float* w4    = (const float*)d_in[5];
    const int*   a_idx = (const int*)d_in[6];
    const int*   b_idx = (const int*)d_in[7];
    float* out = (float*)d_out;

    // ws layout: baseAB (8 KB) | cws (32 KB)
    int*    baseAB = (int*)d_ws;
    float4* cws    = (float4*)((char*)d_ws + (size_t)K_ * 32 * 4);

    prep_kernel<<<16, 256, 0, stream>>>(a_idx, b_idx, w0, w1, w2, w3, w4,
                                        baseAB, cws);

    logicconv_main<<<256, 1024, 0, stream>>>(x, baseAB, cws, out);
}

// Round 12
// 33.645 us; speedup vs baseline: 2.4638x; 2.4638x over previous
//
#include <hip/hip_runtime.h>
#include <hip/hip_bf16.h>

// LogicConv3d: B=64, C=32, H=32, W=32, K=64, P=784, S=16 gathers/side.
// R12: R10 base + parity-split LDS reads implemented WITHOUT arrays.
//  - R11 post-mortem: WRITE_SIZE 87MB (7x output) = scratch spills of the
//    sB/sD swizzle arrays (rule: runtime-ish indexed arrays -> scratch);
//    that, not the swizzle, caused the 82us. Reverted rebalance too.
//  - R10's ds_read2 pair reads have 8B lane stride = even banks = 4-way
//    conflict (~16us of main). Fix: stage even image as two planes
//    se[i]=x[2i] (LDS[0:64K)), so[i]=x[2i+1] (LDS[64K:128K)). Pair (e,e+1)
//    = one read in se + one in so at lane-stride-4B addrs -> conflict-free.
//    Bases computed INLINE as scalar (uniform) expressions from s-loaded
//    bA[l]; loop-invariant -> SGPR-hoisted, no scratch.
//  - Staging: float2 global loads, single-dword LDS writes (stride 4B, free).
//  - Odd image from global, analytic disp, kg-slow grid: unchanged from R10.

#define B_  64
#define C_  32
#define H_  32
#define W_  32
#define K_  64
#define P_  784
#define CHW (C_*H_*W_)      // 32768 floats = 128 KB
#define HW  (H_*W_)         // 1024
#define SITES (K_*P_)       // 50176
#define NPAIR (P_/2)        // 392

__constant__ float COEF_[16][4] = {
    {0, 0, 0, 0}, {0, 0, 0, 1}, {0, 1, 0, -1}, {0, 1, 0, 0},
    {0, 0, 1, -1}, {0, 0, 1, 0}, {0, 1, 1, -2}, {0, 1, 1, -1},
    {1, -1, -1, 1}, {1, -1, -1, 2}, {1, 0, -1, 0}, {1, 0, -1, 1},
    {1, -1, 0, 0}, {1, -1, 0, 1}, {1, 0, 0, -1}, {1, 0, 0, 0}
};

// ---- kernel 1: tiny prep = bases (0..2047) + coefs (2048..4031) ----
__global__ __launch_bounds__(256) void prep_kernel(
    const int* __restrict__ a_idx, const int* __restrict__ b_idx,
    const float* __restrict__ w0, const float* __restrict__ w1,
    const float* __restrict__ w2, const float* __restrict__ w3,
    const float* __restrict__ w4,
    int* __restrict__ baseAB,        // [K_][32] byte offsets
    float4* __restrict__ cws)        // [K_*31]
{
    const int t = blockIdx.x * 256 + threadIdx.x;
    if (t < K_ * 32) {
        const int k = t >> 5;
        const int j = t & 31;
        const int* src = (j < 16) ? a_idx : b_idx;
        const int l = j & 15;
        const size_t ii = ((size_t)k * P_ * 16 + l) * 3;   // site (k, p=0, l)
        const int h = src[ii + 0];
        const int w = src[ii + 1];
        const int c = src[ii + 2];
        baseAB[t] = (c << 12) + (h << 7) + (w << 2);       // bytes
    } else if (t < K_ * 32 + K_ * 31) {
        const int tt = t - K_ * 32;
        const int k = tt / 31;
        const int node = tt - k * 31;
        int d, l;
        if      (node < 16) { d = 0; l = node; }
        else if (node < 24) { d = 1; l = node - 16; }
        else if (node < 28) { d = 2; l = node - 24; }
        else if (node < 30) { d = 3; l = node - 28; }
        else                { d = 4; l = 0; }
        const float* W;
        switch (d) {
            case 0: W = w0; break;
            case 1: W = w1; break;
            case 2: W = w2; break;
            case 3: W = w3; break;
            default: W = w4; break;
        }
        const float* row = W + ((size_t)l * K_ + k) * 16;
        float m = row[0];
        #pragma unroll
        for (int o = 1; o < 16; ++o) m = fmaxf(m, row[o]);
        float e[16];
        float Z = 0.0f;
        #pragma unroll
        for (int o = 0; o < 16; ++o) { e[o] = expf(row[o] - m); Z += e[o]; }
        const float inv = 1.0f / Z;
        float c0 = 0.f, c1 = 0.f, c2 = 0.f, c3 = 0.f;
        #pragma unroll
        for (int o = 0; o < 16; ++o) {
            c0 += e[o] * COEF_[o][0];
            c1 += e[o] * COEF_[o][1];
            c2 += e[o] * COEF_[o][2];
            c3 += e[o] * COEF_[o][3];
        }
        cws[tt] = make_float4(c0 * inv, c1 * inv, c2 * inv, c3 * inv);
    }
}

// y = c0 + c1*a + c2*b + c3*a*b == fma(b, fma(c3,a,c2), fma(c1,a,c0))
__device__ __forceinline__ float binop(float a, float b, float4 c) {
    return fmaf(b, fmaf(c.w, a, c.z), fmaf(c.y, a, c.x));
}

// ---- kernel 2: main. bid = kg*32 + bp. 1024 thr, 1 block/CU. ----
__global__ __launch_bounds__(1024, 4) void logicconv_main(
    const float* __restrict__ x,
    const int* __restrict__ baseAB,
    const float4* __restrict__ cws,
    float* __restrict__ out)
{
    __shared__ float simg[CHW];   // [0:16384) = even elems, [16384:32768) = odd

    const int tid = threadIdx.x;
    const int kg  = blockIdx.x >> 5;   // 0..7  (slow)
    const int bp  = blockIdx.x & 31;   // 0..31 (fast)
    const int b0  = bp * 2;

    // stage EVEN image parity-split: se[i]=x[2i], so[i]=x[2i+1]
    // float2 coalesced loads; single-dword LDS writes (lane stride 4B = free)
    {
        const float2* xi = (const float2*)(x + (size_t)b0 * CHW);
        float* se = simg;            // even elements
        float* so = simg + 16384;    // odd elements (byte 65536)
        #pragma unroll
        for (int j = 0; j < 16; ++j) {
            const int u = tid + j * 1024;
            const float2 v = xi[u];
            se[u] = v.x;
            so[u] = v.y;
        }
    }
    __syncthreads();

    // 8 groups of 128 threads; group owns one k (wave-uniform)
    const int g    = __builtin_amdgcn_readfirstlane(tid >> 7);
    const int lane = tid & 127;
    const int k    = kg * 8 + g;

    const int*    __restrict__ bA = baseAB + k * 32;          // s_load
    const float4* __restrict__ cw = cws + (size_t)k * 31;     // s_load
    const char*   sb = (const char*)simg;
    const char*   x1 = (const char*)(x + (size_t)(b0 + 1) * CHW);  // odd image
    float* __restrict__ o0 = out + ((size_t)b0 * K_ + k) * P_;
    float* __restrict__ o1 = o0 + (size_t)K_ * P_;

    for (int s = 0; s < 4; ++s) {
        const int t = s * 128 + lane;          // pair index
        if (t < NPAIR) {
            const unsigned row   = (unsigned)t / 14u;             // (2t)/28
            const unsigned dispL = 4u * (unsigned)t + 8u * row;   // parity-split
            const unsigned dispG = 8u * (unsigned)t + 16u * row;  // original

            float2 ye[16], yo[16];
            #pragma unroll
            for (int h = 0; h < 2; ++h) {
                // ---- 1) odd-image global loads (8 leaves) ----
                float od[32];
                #pragma unroll
                for (int j = 0; j < 8; ++j) {
                    const int l = h * 8 + j;
                    const unsigned ea = (unsigned)bA[l]      + dispG;
                    const unsigned eb = (unsigned)bA[16 + l] + dispG;
                    od[4*j+0] = *(const float*)(x1 + ea);
                    od[4*j+1] = *(const float*)(x1 + ea + 4);
                    od[4*j+2] = *(const float*)(x1 + eb);
                    od[4*j+3] = *(const float*)(x1 + eb + 4);
                }
                // ---- 2) even-image LDS reads, parity-split (conflict-free)
                //  elem e   -> (e&1 ? so : se)[e>>1]
                //  elem e+1 -> (e&1 ? se[(e>>1)+1] : so[e>>1])
                //  bases are uniform scalar exprs of bA -> SGPR, no arrays
                float ev[32];
                #pragma unroll
                for (int j = 0; j < 8; ++j) {
                    const int l = h * 8 + j;
                    const int beA = bA[l] >> 2;
                    const int beB = bA[16 + l] >> 2;
                    const unsigned hA = (unsigned)(beA >> 1) << 2;
                    const unsigned hB = (unsigned)(beB >> 1) << 2;
                    const unsigned loA = ((beA & 1) ? 65536u + hA : hA);
                    const unsigned hiA = ((beA & 1) ? hA + 4u : 65536u + hA);
                    const unsigned loB = ((beB & 1) ? 65536u + hB : hB);
                    const unsigned hiB = ((beB & 1) ? hB + 4u : 65536u + hB);
                    ev[4*j+0] = *(const float*)(sb + loA + dispL);
                    ev[4*j+1] = *(const float*)(sb + hiA + dispL);
                    ev[4*j+2] = *(const float*)(sb + loB + dispL);
                    ev[4*j+3] = *(const float*)(sb + hiB + dispL);
                }
                // ---- 3) layer-0 for this half ----
                #pragma unroll
                for (int j = 0; j < 8; ++j) {
                    const int l = h * 8 + j;
                    const float4 c = cw[l];
                    ye[l].x = binop(ev[4*j+0], ev[4*j+2], c);
                    ye[l].y = binop(ev[4*j+1], ev[4*j+3], c);
                    yo[l].x = binop(od[4*j+0], od[4*j+2], c);
                    yo[l].y = binop(od[4*j+1], od[4*j+3], c);
                }
            }
            #pragma unroll
            for (int l = 0; l < 8; ++l) {
                const float4 c = cw[16 + l];
                ye[l].x = binop(ye[2*l].x, ye[2*l+1].x, c);
                ye[l].y = binop(ye[2*l].y, ye[2*l+1].y, c);
                yo[l].x = binop(yo[2*l].x, yo[2*l+1].x, c);
                yo[l].y = binop(yo[2*l].y, yo[2*l+1].y, c);
            }
            #pragma unroll
            for (int l = 0; l < 4; ++l) {
                const float4 c = cw[24 + l];
                ye[l].x = binop(ye[2*l].x, ye[2*l+1].x, c);
                ye[l].y = binop(ye[2*l].y, ye[2*l+1].y, c);
                yo[l].x = binop(yo[2*l].x, yo[2*l+1].x, c);
                yo[l].y = binop(yo[2*l].y, yo[2*l+1].y, c);
            }
            #pragma unroll
            for (int l = 0; l < 2; ++l) {
                const float4 c = cw[28 + l];
                ye[l].x = binop(ye[2*l].x, ye[2*l+1].x, c);
                ye[l].y = binop(ye[2*l].y, ye[2*l+1].y, c);
                yo[l].x = binop(yo[2*l].x, yo[2*l+1].x, c);
                yo[l].y = binop(yo[2*l].y, yo[2*l+1].y, c);
            }
            {
                const float4 c = cw[30];
                float2 re, ro;
                re.x = binop(ye[0].x, ye[1].x, c);
                re.y = binop(ye[0].y, ye[1].y, c);
                ro.x = binop(yo[0].x, yo[1].x, c);
                ro.y = binop(yo[0].y, yo[1].y, c);
                *(float2*)(o0 + 2 * t) = re;   // byte 8t -> 8-aligned
                *(float2*)(o1 + 2 * t) = ro;
            }
        }
    }
}

extern "C" void kernel_launch(void* const* d_in, const int* in_sizes, int n_in,
                              void* d_out, int out_size, void* d_ws, size_t ws_size,
                              hipStream_t stream) {
    const float* x     = (const float*)d_in[0];
    const float* w0    = (const float*)d_in[1];
    const float* w1    = (const float*)d_in[2];
    const float* w2    = (const float*)d_in[3];
    const float* w3    = (const float*)d_in[4];
    const float* w4    = (const float*)d_in[5];
    const int*   a_idx = (const int*)d_in[6];
    const int*   b_idx = (const int*)d_in[7];
    float* out = (float*)d_out;

    // ws layout: baseAB (8 KB) | cws (32 KB)
    int*    baseAB = (int*)d_ws;
    float4* cws    = (float4*)((char*)d_ws + (size_t)K_ * 32 * 4);

    prep_kernel<<<16, 256, 0, stream>>>(a_idx, b_idx, w0, w1, w2, w3, w4,
                                        baseAB, cws);

    logicconv_main<<<256, 1024, 0, stream>>>(x, baseAB, cws, out);
}